// Round 1
// baseline (227.286 us; speedup 1.0000x reference)
//
#include <hip/hip_runtime.h>

// RandomShifts: out[n,c,i,j] = x[n,c, clamp(i+sy-PAD,0,H-1), clamp(j+sx-PAD,0,W-1)]
// x: (512, 9, 84, 84) fp32, shift: (512, 2) int32 (sx, sy). Memory-bound.

#define PADN 4
#define NB   512
#define CB   9
#define HB   84
#define WB   84
#define W4   (WB / 4)   // 21 float4 per row; rows are 336 B = 16B-aligned stride

// 4-byte-aligned 16-byte load: HW supports dword-aligned dwordx4; this avoids
// the UB of casting a misaligned pointer to float4*.
struct __attribute__((packed, aligned(4))) f4u { float a, b, c, d; };

__global__ __launch_bounds__(256) void random_shifts_kernel(
    const float* __restrict__ x,
    const int*   __restrict__ shift,
    float*       __restrict__ out,
    int total /* = NB*CB*HB*W4 */)
{
    const int stride = gridDim.x * blockDim.x;
    for (int t = blockIdx.x * blockDim.x + threadIdx.x; t < total; t += stride) {
        const int j4 = t % W4;          // which float4 within the row
        const int r  = t / W4;          // flat row id = (n*CB + c)*HB + i
        const int i  = r % HB;
        const int nc = r / HB;          // n*CB + c
        const int n  = nc / CB;

        const int sx = shift[2 * n];
        const int sy = shift[2 * n + 1];

        int si = i + sy - PADN;
        si = si < 0 ? 0 : (si > HB - 1 ? HB - 1 : si);

        const float* srow = x + ((size_t)nc * HB + si) * WB;

        const int j  = j4 * 4;
        const int cs = j + sx - PADN;   // first source column, in [-4, 87]

        float4 v;
        if (cs >= 0 && cs + 3 <= WB - 1) {
            // interior: contiguous shifted run, 4B-aligned vector load
            const f4u u = *reinterpret_cast<const f4u*>(srow + cs);
            v = make_float4(u.a, u.b, u.c, u.d);
        } else {
            // row edge: per-element replicate clamp (only lanes with j4==0 or 20)
            const int c0 = min(max(cs,     0), WB - 1);
            const int c1 = min(max(cs + 1, 0), WB - 1);
            const int c2 = min(max(cs + 2, 0), WB - 1);
            const int c3 = min(max(cs + 3, 0), WB - 1);
            v = make_float4(srow[c0], srow[c1], srow[c2], srow[c3]);
        }

        // output float4 t is 16B-aligned by construction
        *reinterpret_cast<float4*>(out + (size_t)t * 4) = v;
    }
}

extern "C" void kernel_launch(void* const* d_in, const int* in_sizes, int n_in,
                              void* d_out, int out_size, void* d_ws, size_t ws_size,
                              hipStream_t stream) {
    const float* x     = (const float*)d_in[0];
    const int*   shift = (const int*)d_in[1];
    float*       out   = (float*)d_out;

    const int total = NB * CB * HB * W4;   // 8,128,512 float4s
    const int threads = 256;
    const int blocks  = 2048;              // grid-stride, ~8 blocks/CU
    random_shifts_kernel<<<blocks, threads, 0, stream>>>(x, shift, out, total);
}